// Round 11
// baseline (166.744 us; speedup 1.0000x reference)
//
#include <hip/hip_runtime.h>
#include <cmath>

// SSIM loss, BARRIER-FREE wave-strip kernel.
// Round-11 insight: occupancy is stuck ~45% regardless of LDS size (R6/R9/R10)
// because the per-row write|barrier|read lockstep serializes all waves. Fix:
// each WAVE owns an independent 116-col output strip (64 lanes = 64 input
// pairs incl. 3-pair halo each side; outputs = pairs 3..60). A wave reads
// only LDS it wrote itself -> DS ops complete in-order per wave -> NO
// __syncthreads anywhere. 512-col row = 5 strips (4x58 + 1x24 output pairs).
// 4 waves/block are fully independent work units (3D and 2D mixed freely);
// per-wave shuffle reduction + one atomicAdd per wave.
// Math identical to R9: f32x2 packed (v_pk_fma_f32), 11-slot register ring,
// vertical-first, per-pair LDS channels A4=(m1,m2) B4=(xx,yy) Z2=zz at 16B
// lane stride (conflict-free). launch_bounds(256,5) = proven no-spill.

#define WSZ 11
#define IMG 512
#define SLICE (IMG * IMG)

typedef float f32x2 __attribute__((ext_vector_type(2)));
typedef float f32x4 __attribute__((ext_vector_type(4)));

struct G11 { float w[WSZ]; };

__global__ __launch_bounds__(256, 5)
void ssim_ws_kernel(const float* __restrict__ A3, const float* __restrict__ B3,
                    const float* __restrict__ A2, const float* __restrict__ B2,
                    double* __restrict__ acc, G11 gw)
{
    // per-wave private regions; 70 slots = 64 pairs + 3 pad each side
    __shared__ f32x4 A4[4][70];
    __shared__ f32x4 B4[4][70];
    __shared__ f32x2 Z2[4][70];

    const int tx   = threadIdx.x;
    const int wid  = tx >> 6;
    const int lane = tx & 63;

    // unit decode: 8200 wave-units, 4 per block.
    //  [0,7680)    3D: 64 slices x 24 bands (8x22 + 16x21 rows) x 5 strips
    //  [7680,8200) 2D: 4 imgs x 26 bands (18x20 + 8x19 rows) x 5 strips
    const int u = blockIdx.x * 4 + wid;
    const float* Ap; const float* Bp; double* accp;
    int y0, BND, strip;
    if (u < 7680) {
        int slice = u / 120;
        int r = u - slice * 120;
        int band = r / 5; strip = r - band * 5;
        Ap = A3 + (long)slice * SLICE;
        Bp = B3 + (long)slice * SLICE;
        accp = acc + 0;
        if (band < 8) { y0 = band * 22;              BND = 22; }
        else          { y0 = 176 + (band - 8) * 21;  BND = 21; }
    } else {
        int u2 = u - 7680;
        int img = u2 / 130;
        int r2 = u2 - img * 130;
        int band = r2 / 5; strip = r2 - band * 5;
        Ap = A2 + (long)img * SLICE;
        Bp = B2 + (long)img * SLICE;       // B2 = precomputed depth-16 mean
        accp = acc + 1;
        if (band < 18) { y0 = band * 20;              BND = 20; }
        else           { y0 = 360 + (band - 18) * 19; BND = 19; }
    }
    const int TST = BND + 10;
    const int ip  = strip * 58 - 3 + lane;   // this lane's input pair index
    const bool vin  = (ip >= 0) && (ip < 256);
    const bool vout = (lane >= 3) && (lane <= 60) && (ip < 256);
    const int x0 = 2 * ip;                   // col of pair (guarded by vin)

    // zero the halo pad slots (0..2, 67..69) of this wave's region; read-only
    // thereafter. Same-wave write->read needs no barrier.
    if (lane < 3) {
        A4[wid][lane] = (f32x4){0.f, 0.f, 0.f, 0.f};
        B4[wid][lane] = (f32x4){0.f, 0.f, 0.f, 0.f};
        Z2[wid][lane] = (f32x2){0.f, 0.f};
    } else if (lane >= 61) {
        A4[wid][lane + 6] = (f32x4){0.f, 0.f, 0.f, 0.f};
        B4[wid][lane + 6] = (f32x4){0.f, 0.f, 0.f, 0.f};
        Z2[wid][lane + 6] = (f32x2){0.f, 0.f};
    }

    // 11-slot register ring of raw (a,b) pairs, statically indexed (unroll-11)
    f32x2 ra[11], rb[11];
    #pragma unroll
    for (int i = 0; i < 11; i++) { ra[i] = (f32x2){0.f, 0.f}; rb[i] = (f32x2){0.f, 0.f}; }

    float sum = 0.f;

    // prefetch first input row (r = y0 - 5)
    f32x2 aN = {0.f, 0.f}, bN = {0.f, 0.f};
    {
        int r = y0 - 5;
        if (r >= 0 && r < IMG && vin) {
            aN = *(const f32x2*)&Ap[(long)r * IMG + x0];
            bN = *(const f32x2*)&Bp[(long)r * IMG + x0];
        }
    }

    const f32x2 C1v = {1e-4f, 1e-4f};
    const f32x2 C2v = {9e-4f, 9e-4f};

    for (int t0 = 0; t0 < TST; t0 += 11) {
        #pragma unroll
        for (int uu = 0; uu < 11; uu++) {
            const int t = t0 + uu;
            if (t < TST) {                    // wave-uniform
                ra[uu] = aN;
                rb[uu] = bN;

                // prefetch next row (row guard wave-uniform, vin lane-masked)
                {
                    int rn = y0 - 4 + t;
                    aN = (f32x2){0.f, 0.f}; bN = (f32x2){0.f, 0.f};
                    if ((t + 1 < TST) && rn >= 0 && rn < IMG && vin) {
                        aN = *(const f32x2*)&Ap[(long)rn * IMG + x0];
                        bN = *(const f32x2*)&Bp[(long)rn * IMG + x0];
                    }
                }

                if (t >= 10) {                // output row o = y0 + t - 10
                    // vertical 11-tap (packed): slot (uu+1+j)%11 = row o-5+j
                    f32x2 m1 = {0.f, 0.f}, m2 = m1, xx = m1, yy = m1, zz = m1;
                    #pragma unroll
                    for (int j = 0; j < 11; j++) {
                        const int s = (uu + 1 + j) % 11;    // compile-time
                        const f32x2 g2 = {gw.w[j], gw.w[j]};
                        f32x2 a = ra[s], b = rb[s];
                        f32x2 ga = g2 * a, gb = g2 * b;
                        m1 += ga; m2 += gb;
                        xx += ga * a; yy += gb * b; zz += ga * b;
                    }
                    // write own slot; same-wave readers below, no barrier
                    A4[wid][lane + 3] = __builtin_shufflevector(m1, m2, 0, 1, 2, 3);
                    B4[wid][lane + 3] = __builtin_shufflevector(xx, yy, 0, 1, 2, 3);
                    Z2[wid][lane + 3] = zz;

                    // horizontal 11-tap over 7 pair slots (lane..lane+6),
                    // packed coefficients; slot lane+jj holds cols
                    // (x0-6+2jj, x0-5+2jj) for this lane's output pair.
                    f32x2 OM1 = {0.f, 0.f}, OM2 = OM1, OXX = OM1, OYY = OM1, OZZ = OM1;
                    {   // jj = 0: only e1 with (g0, 0)
                        f32x4 pa = A4[wid][lane], pb = B4[wid][lane];
                        f32x2 pz = Z2[wid][lane];
                        const f32x2 c = {gw.w[0], 0.f};
                        OM1 += c * __builtin_shufflevector(pa, pa, 1, 1);
                        OM2 += c * __builtin_shufflevector(pa, pa, 3, 3);
                        OXX += c * __builtin_shufflevector(pb, pb, 1, 1);
                        OYY += c * __builtin_shufflevector(pb, pb, 3, 3);
                        OZZ += c * __builtin_shufflevector(pz, pz, 1, 1);
                    }
                    #pragma unroll
                    for (int jj = 1; jj <= 5; jj++) {
                        f32x4 pa = A4[wid][lane + jj], pb = B4[wid][lane + jj];
                        f32x2 pz = Z2[wid][lane + jj];
                        const f32x2 cA = {gw.w[2 * jj - 1], gw.w[2 * jj - 2]};
                        const f32x2 cB = {gw.w[2 * jj],     gw.w[2 * jj - 1]};
                        OM1 += cA * __builtin_shufflevector(pa, pa, 0, 0)
                             + cB * __builtin_shufflevector(pa, pa, 1, 1);
                        OM2 += cA * __builtin_shufflevector(pa, pa, 2, 2)
                             + cB * __builtin_shufflevector(pa, pa, 3, 3);
                        OXX += cA * __builtin_shufflevector(pb, pb, 0, 0)
                             + cB * __builtin_shufflevector(pb, pb, 1, 1);
                        OYY += cA * __builtin_shufflevector(pb, pb, 2, 2)
                             + cB * __builtin_shufflevector(pb, pb, 3, 3);
                        OZZ += cA * __builtin_shufflevector(pz, pz, 0, 0)
                             + cB * __builtin_shufflevector(pz, pz, 1, 1);
                    }
                    {   // jj = 6: only e0 with (0, g10)
                        f32x4 pa = A4[wid][lane + 6], pb = B4[wid][lane + 6];
                        f32x2 pz = Z2[wid][lane + 6];
                        const f32x2 c = {0.f, gw.w[10]};
                        OM1 += c * __builtin_shufflevector(pa, pa, 0, 0);
                        OM2 += c * __builtin_shufflevector(pa, pa, 2, 2);
                        OXX += c * __builtin_shufflevector(pb, pb, 0, 0);
                        OYY += c * __builtin_shufflevector(pb, pb, 2, 2);
                        OZZ += c * __builtin_shufflevector(pz, pz, 0, 0);
                    }

                    // SSIM formula, packed where possible
                    f32x2 m1s = OM1 * OM1, m2s = OM2 * OM2, m12 = OM1 * OM2;
                    f32x2 s1 = OXX - m1s, s2 = OYY - m2s, s12 = OZZ - m12;
                    f32x2 d1 = m1s + m2s + C1v;
                    f32x2 d2 = s1 + s2 + C2v;
                    f32x2 num = (2.f * m12 + C1v) * (2.f * s12 + C2v) * (s12 + C2v);
                    float d3x = __builtin_amdgcn_sqrtf(s1.x) * __builtin_amdgcn_sqrtf(s2.x) + 9e-4f;
                    float d3y = __builtin_amdgcn_sqrtf(s1.y) * __builtin_amdgcn_sqrtf(s2.y) + 9e-4f;
                    float contrib = num.x * __builtin_amdgcn_rcpf(d1.x * d2.x * d3x)
                                  + num.y * __builtin_amdgcn_rcpf(d1.y * d2.y * d3y);
                    sum += vout ? contrib : 0.f;
                }
            }
        }
    }

    // per-wave reduction (waves have different accp!) -> one atomic per wave
    for (int off = 32; off > 0; off >>= 1)
        sum += __shfl_down(sum, off, 64);
    if (lane == 0)
        atomicAdd(accp, (double)sum);
}

// b2 = mean over 16 depth slices of img2, vectorized float4 (BW-bound).
__global__ __launch_bounds__(256) void depth_mean4_kernel(
    const float4* __restrict__ img2, float4* __restrict__ b2)
{
    const int per = SLICE / 4;                       // 65536 float4 per slice
    int idx = blockIdx.x * 256 + threadIdx.x;        // 0 .. 4*per-1
    int b = idx >> 16;
    int p = idx & (per - 1);
    const float4* src = img2 + (long)b * 16 * per + p;
    float sx = 0.f, sy = 0.f, sz = 0.f, sw = 0.f;
    #pragma unroll
    for (int d = 0; d < 16; d++) {
        float4 v = src[(long)d * per];
        sx += v.x; sy += v.y; sz += v.z; sw += v.w;
    }
    float4 o; o.x = sx * 0.0625f; o.y = sy * 0.0625f; o.z = sz * 0.0625f; o.w = sw * 0.0625f;
    b2[idx] = o;
}

__global__ void finalize_kernel(const double* __restrict__ acc, float* __restrict__ out)
{
    double loss3 = 1.0 - acc[0] / (64.0 * (double)SLICE);
    double loss2 = 1.0 - acc[1] / (4.0 * (double)SLICE);
    out[0] = (float)(loss3 + loss2);
}

extern "C" void kernel_launch(void* const* d_in, const int* in_sizes, int n_in,
                              void* d_out, int out_size, void* d_ws, size_t ws_size,
                              hipStream_t stream)
{
    const float* img1_3d = (const float*)d_in[0];   // [4,1,16,512,512] -> 64 slices
    const float* img1_2d = (const float*)d_in[1];   // [4,1,512,512]
    const float* img2    = (const float*)d_in[2];   // [4,1,16,512,512]
    float* out = (float*)d_out;

    double* acc = (double*)d_ws;                    // [0]=3D sum, [1]=2D sum
    float*  b2  = (float*)((char*)d_ws + 256);      // 4 MB depth-mean buffer

    // Gaussian weights, like cv2.getGaussianKernel(11, 1.5) in double.
    G11 gw;
    {
        double g[WSZ], s = 0.0;
        for (int i = 0; i < WSZ; i++) {
            double xx = (double)i - (WSZ - 1) / 2.0;
            g[i] = std::exp(-(xx * xx) / (2.0 * 1.5 * 1.5));
            s += g[i];
        }
        for (int i = 0; i < WSZ; i++) gw.w[i] = (float)(g[i] / s);
    }

    hipMemsetAsync(acc, 0, 2 * sizeof(double), stream);

    // depth mean of img2 -> b2 (68 MB, ~12 us, proven)
    depth_mean4_kernel<<<(4 * SLICE / 4) / 256, 256, 0, stream>>>(
        (const float4*)img2, (float4*)b2);

    // barrier-free wave-strip SSIM: 8200 wave-units / 4 per block = 2050 blocks
    ssim_ws_kernel<<<2050, 256, 0, stream>>>(img1_3d, img2, img1_2d, b2, acc, gw);

    finalize_kernel<<<1, 1, 0, stream>>>(acc, out);
}

// Round 12
// 122.854 us; speedup vs baseline: 1.3573x; 1.3573x over previous
//
#include <hip/hip_runtime.h>
#include <cmath>

// SSIM loss, vertical-first row-sliding kernel, merged 3D+2D dispatch.
// Round-12 = round-9 kernel (proven best: launch_bounds(256,5) -> 48 VGPR no
// spill, 21 KB double-buffered LDS, 1 barrier/output row, 0 bank conflicts)
// with the serial depth-mean dispatch ELIMINATED: 2D units compute the
// depth-16 mean of img2 inline in their B-row loads (R10 proved no spill)
// and are placed FIRST in the grid so their 16x fetches overlap under the
// 3D bulk instead of tailing (R10's mistake).
// Block = 256 threads, each owns 2 adjacent columns; all math in f32x2
// ext-vectors (v_pk_*_f32). LDS per column-PAIR: A4=(m1,m2) B4=(xx,yy)
// Z2=zz; horizontal taps = 7 slot reads at 16B lane stride (conflict-free)
// with compile-time packed coefficient pairs.

#define WSZ 11
#define IMG 512
#define SLICE (IMG * IMG)

typedef float f32x2 __attribute__((ext_vector_type(2)));
typedef float f32x4 __attribute__((ext_vector_type(4)));

struct G11 { float w[WSZ]; };

__global__ __launch_bounds__(256, 5)
void ssim_pk_kernel(const float* __restrict__ A3, const float* __restrict__ B3,
                    const float* __restrict__ A2,
                    double* __restrict__ acc, G11 gw)
{
    __shared__ f32x4 A4[2][262];   // (m1,m2) pairs, 3-slot pad each side
    __shared__ f32x4 B4[2][262];   // (xx,yy) pairs
    __shared__ f32x2 Z2[2][262];   // zz pairs
    __shared__ float bsum[4];

    const int tx = threadIdx.x;    // 0..255 = column pair index
    const int x0 = tx * 2;

    // decode work unit:
    //  [0,256)    = 2D bands FIRST (4 imgs x 64 bands of 8 rows), B = mean16(img2)
    //  [256,1792) = 3D slice-bands: 64 slices x 24 bands (16x22 + 8x20 rows)
    const int unit = blockIdx.x;
    const bool m16 = (unit < 256);
    const float* Ap;
    const float* Bp;
    double* accp;
    int y0, TST;
    if (m16) {
        int img  = unit >> 6;
        int band = unit & 63;
        Ap = A2 + (long)img * SLICE;
        Bp = B3 + (long)img * 16 * SLICE;   // img2[img, 0..15] for inline mean
        accp = acc + 1;
        y0 = band * 8;
        TST = 8 + 10;
    } else {
        int uu = unit - 256;
        int slice = uu / 24;
        int band  = uu - slice * 24;
        Ap = A3 + (long)slice * SLICE;
        Bp = B3 + (long)slice * SLICE;
        accp = acc + 0;
        if (band < 16) { y0 = band * 22;              TST = 22 + 10; }
        else           { y0 = 352 + (band - 16) * 20; TST = 20 + 10; }
    }

    // B-row loader: plain row for 3D, inline 16-slice mean for 2D
    auto loadB = [&](int r) -> f32x2 {
        if (!m16) return *(const f32x2*)&Bp[(long)r * IMG + x0];
        f32x2 s = {0.f, 0.f};
        #pragma unroll
        for (int d = 0; d < 16; d++)
            s += *(const f32x2*)&Bp[(long)d * SLICE + (long)r * IMG + x0];
        return s * 0.0625f;
    };

    // zero pads: pair slots 0..2 and 259..261, both buffers
    if (tx < 3) {
        f32x4 z4 = {0.f, 0.f, 0.f, 0.f};
        f32x2 z2 = {0.f, 0.f};
        A4[0][tx] = z4; A4[1][tx] = z4; A4[0][259 + tx] = z4; A4[1][259 + tx] = z4;
        B4[0][tx] = z4; B4[1][tx] = z4; B4[0][259 + tx] = z4; B4[1][259 + tx] = z4;
        Z2[0][tx] = z2; Z2[1][tx] = z2; Z2[0][259 + tx] = z2; Z2[1][259 + tx] = z2;
    }

    // 11-slot register ring of raw (a,b) pairs, statically indexed (unroll-11)
    f32x2 ra[11], rb[11];
    #pragma unroll
    for (int i = 0; i < 11; i++) { ra[i] = (f32x2){0.f, 0.f}; rb[i] = (f32x2){0.f, 0.f}; }

    float sum = 0.f;

    // prefetch first input row (r = y0 - 5)
    f32x2 aN = {0.f, 0.f}, bN = {0.f, 0.f};
    {
        int r = y0 - 5;
        if (r >= 0 && r < IMG) {
            aN = *(const f32x2*)&Ap[(long)r * IMG + x0];
            bN = loadB(r);
        }
    }

    const f32x2 C1v = {1e-4f, 1e-4f};
    const f32x2 C2v = {9e-4f, 9e-4f};

    for (int t0 = 0; t0 < TST; t0 += 11) {
        #pragma unroll
        for (int u = 0; u < 11; u++) {
            const int t = t0 + u;
            if (t < TST) {                    // block-uniform
                ra[u] = aN;
                rb[u] = bN;

                // prefetch next row (block-uniform guard)
                {
                    int rn = y0 - 4 + t;
                    aN = (f32x2){0.f, 0.f}; bN = (f32x2){0.f, 0.f};
                    if ((t + 1 < TST) && rn >= 0 && rn < IMG) {
                        aN = *(const f32x2*)&Ap[(long)rn * IMG + x0];
                        bN = loadB(rn);
                    }
                }

                if (t >= 10) {                // output row o = y0 + t - 10
                    // vertical 11-tap (packed): slot (u+1+j)%11 = row o-5+j
                    f32x2 m1 = {0.f, 0.f}, m2 = m1, xx = m1, yy = m1, zz = m1;
                    #pragma unroll
                    for (int j = 0; j < 11; j++) {
                        const int s = (u + 1 + j) % 11;     // compile-time
                        const f32x2 g2 = {gw.w[j], gw.w[j]};
                        f32x2 a = ra[s], b = rb[s];
                        f32x2 ga = g2 * a, gb = g2 * b;
                        m1 += ga; m2 += gb;
                        xx += ga * a; yy += gb * b; zz += ga * b;
                    }
                    const int buf = t & 1;
                    A4[buf][3 + tx] = __builtin_shufflevector(m1, m2, 0, 1, 2, 3);
                    B4[buf][3 + tx] = __builtin_shufflevector(xx, yy, 0, 1, 2, 3);
                    Z2[buf][3 + tx] = zz;
                    __syncthreads();

                    // horizontal 11-tap over 7 pair slots, packed coefficients.
                    // slot jj holds cols (x0-6+2jj, x0-5+2jj); for output pair
                    // (x0, x0+1): e0 coeffs (g[2jj-1], g[2jj-2]), e1 (g[2jj], g[2jj-1]).
                    f32x2 OM1 = {0.f, 0.f}, OM2 = OM1, OXX = OM1, OYY = OM1, OZZ = OM1;
                    {   // jj = 0: only e1 with (g0, 0)
                        f32x4 pa = A4[buf][tx], pb = B4[buf][tx];
                        f32x2 pz = Z2[buf][tx];
                        const f32x2 c = {gw.w[0], 0.f};
                        OM1 += c * __builtin_shufflevector(pa, pa, 1, 1);
                        OM2 += c * __builtin_shufflevector(pa, pa, 3, 3);
                        OXX += c * __builtin_shufflevector(pb, pb, 1, 1);
                        OYY += c * __builtin_shufflevector(pb, pb, 3, 3);
                        OZZ += c * __builtin_shufflevector(pz, pz, 1, 1);
                    }
                    #pragma unroll
                    for (int jj = 1; jj <= 5; jj++) {
                        f32x4 pa = A4[buf][tx + jj], pb = B4[buf][tx + jj];
                        f32x2 pz = Z2[buf][tx + jj];
                        const f32x2 cA = {gw.w[2 * jj - 1], gw.w[2 * jj - 2]};
                        const f32x2 cB = {gw.w[2 * jj],     gw.w[2 * jj - 1]};
                        OM1 += cA * __builtin_shufflevector(pa, pa, 0, 0)
                             + cB * __builtin_shufflevector(pa, pa, 1, 1);
                        OM2 += cA * __builtin_shufflevector(pa, pa, 2, 2)
                             + cB * __builtin_shufflevector(pa, pa, 3, 3);
                        OXX += cA * __builtin_shufflevector(pb, pb, 0, 0)
                             + cB * __builtin_shufflevector(pb, pb, 1, 1);
                        OYY += cA * __builtin_shufflevector(pb, pb, 2, 2)
                             + cB * __builtin_shufflevector(pb, pb, 3, 3);
                        OZZ += cA * __builtin_shufflevector(pz, pz, 0, 0)
                             + cB * __builtin_shufflevector(pz, pz, 1, 1);
                    }
                    {   // jj = 6: only e0 with (0, g10)
                        f32x4 pa = A4[buf][tx + 6], pb = B4[buf][tx + 6];
                        f32x2 pz = Z2[buf][tx + 6];
                        const f32x2 c = {0.f, gw.w[10]};
                        OM1 += c * __builtin_shufflevector(pa, pa, 0, 0);
                        OM2 += c * __builtin_shufflevector(pa, pa, 2, 2);
                        OXX += c * __builtin_shufflevector(pb, pb, 0, 0);
                        OYY += c * __builtin_shufflevector(pb, pb, 2, 2);
                        OZZ += c * __builtin_shufflevector(pz, pz, 0, 0);
                    }

                    // SSIM formula, packed where possible
                    f32x2 m1s = OM1 * OM1, m2s = OM2 * OM2, m12 = OM1 * OM2;
                    f32x2 s1 = OXX - m1s, s2 = OYY - m2s, s12 = OZZ - m12;
                    f32x2 d1 = m1s + m2s + C1v;
                    f32x2 d2 = s1 + s2 + C2v;
                    f32x2 num = (2.f * m12 + C1v) * (2.f * s12 + C2v) * (s12 + C2v);
                    float d3x = __builtin_amdgcn_sqrtf(s1.x) * __builtin_amdgcn_sqrtf(s2.x) + 9e-4f;
                    float d3y = __builtin_amdgcn_sqrtf(s1.y) * __builtin_amdgcn_sqrtf(s2.y) + 9e-4f;
                    sum += num.x * __builtin_amdgcn_rcpf(d1.x * d2.x * d3x);
                    sum += num.y * __builtin_amdgcn_rcpf(d1.y * d2.y * d3y);
                }
            }
        }
    }

    // block reduction: wave shuffle -> LDS -> one atomic per block
    for (int off = 32; off > 0; off >>= 1)
        sum += __shfl_down(sum, off, 64);
    if ((tx & 63) == 0) bsum[tx >> 6] = sum;
    __syncthreads();
    if (tx == 0) {
        float tot = bsum[0] + bsum[1] + bsum[2] + bsum[3];
        atomicAdd(accp, (double)tot);
    }
}

__global__ void finalize_kernel(const double* __restrict__ acc, float* __restrict__ out)
{
    double loss3 = 1.0 - acc[0] / (64.0 * (double)SLICE);
    double loss2 = 1.0 - acc[1] / (4.0 * (double)SLICE);
    out[0] = (float)(loss3 + loss2);
}

extern "C" void kernel_launch(void* const* d_in, const int* in_sizes, int n_in,
                              void* d_out, int out_size, void* d_ws, size_t ws_size,
                              hipStream_t stream)
{
    const float* img1_3d = (const float*)d_in[0];   // [4,1,16,512,512] -> 64 slices
    const float* img1_2d = (const float*)d_in[1];   // [4,1,512,512]
    const float* img2    = (const float*)d_in[2];   // [4,1,16,512,512]
    float* out = (float*)d_out;

    double* acc = (double*)d_ws;                    // [0]=3D sum, [1]=2D sum

    // Gaussian weights, like cv2.getGaussianKernel(11, 1.5) in double.
    G11 gw;
    {
        double g[WSZ], s = 0.0;
        for (int i = 0; i < WSZ; i++) {
            double xx = (double)i - (WSZ - 1) / 2.0;
            g[i] = std::exp(-(xx * xx) / (2.0 * 1.5 * 1.5));
            s += g[i];
        }
        for (int i = 0; i < WSZ; i++) gw.w[i] = (float)(g[i] / s);
    }

    hipMemsetAsync(acc, 0, 2 * sizeof(double), stream);

    // merged SSIM: 256 2D bands FIRST (inline mean16), then 1536 3D bands
    // (64 slices x (16x22 + 8x20 rows)) = 1792 blocks.
    ssim_pk_kernel<<<1792, 256, 0, stream>>>(img1_3d, img2, img1_2d, acc, gw);

    finalize_kernel<<<1, 1, 0, stream>>>(acc, out);
}

// Round 13
// 105.449 us; speedup vs baseline: 1.5813x; 1.1651x over previous
//
#include <hip/hip_runtime.h>
#include <cmath>

// SSIM loss, vertical-first row-sliding kernel, merged 3D+2D dispatch.
// Round-13 = round-9 (proven best: launch_bounds(256,5) -> 48 VGPR no spill,
// 21 KB double-buffered LDS, 1 barrier/output row, 0 bank conflicts,
// separate depth-mean kernel, 1792-block grid) with ONE change:
// the per-row __syncthreads is replaced by lgkmcnt(0)-wait + raw s_barrier.
// hipcc's __syncthreads drains vmcnt(0) too (m97: "s_waitcnt vmcnt(0)
// lgkmcnt(0)" before s_barrier), which serializes the next-row global
// prefetch latency (~200-900 cyc) into EVERY row step. The barrier only
// needs LDS visibility; with the raw barrier the prefetch stays in flight
// and its latency is absorbed at next step's ring-insert use.

#define WSZ 11
#define IMG 512
#define SLICE (IMG * IMG)

typedef float f32x2 __attribute__((ext_vector_type(2)));
typedef float f32x4 __attribute__((ext_vector_type(4)));

struct G11 { float w[WSZ]; };

// LDS-visibility-only barrier: wait own LDS ops, then rendezvous.
// Does NOT drain vmcnt -> global prefetch loads stay in flight.
__device__ __forceinline__ void row_barrier()
{
    asm volatile("s_waitcnt lgkmcnt(0)" ::: "memory");
    __builtin_amdgcn_s_barrier();
}

__global__ __launch_bounds__(256, 5)
void ssim_pk_kernel(const float* __restrict__ A3, const float* __restrict__ B3,
                    const float* __restrict__ A2, const float* __restrict__ B2,
                    double* __restrict__ acc, G11 gw)
{
    __shared__ f32x4 A4[2][262];   // (m1,m2) pairs, 3-slot pad each side
    __shared__ f32x4 B4[2][262];   // (xx,yy) pairs
    __shared__ f32x2 Z2[2][262];   // zz pairs
    __shared__ float bsum[4];

    const int tx = threadIdx.x;    // 0..255 = column pair index
    const int x0 = tx * 2;

    // decode work unit: [0,1536) = 3D slice-bands (24/slice: 16x22 + 8x20 rows),
    // [1536,1792) = 2D bands (4 imgs x 64 bands of 8 rows, B2 = depth mean)
    const int unit = blockIdx.x;
    const float* Ap;
    const float* Bp;
    double* accp;
    int y0, TST;
    if (unit < 1536) {
        int slice = unit / 24;
        int band  = unit - slice * 24;
        Ap = A3 + (long)slice * SLICE;
        Bp = B3 + (long)slice * SLICE;
        accp = acc + 0;
        if (band < 16) { y0 = band * 22;              TST = 22 + 10; }
        else           { y0 = 352 + (band - 16) * 20; TST = 20 + 10; }
    } else {
        int uu = unit - 1536;
        int img  = uu >> 6;
        int band = uu & 63;
        Ap = A2 + (long)img * SLICE;
        Bp = B2 + (long)img * SLICE;
        accp = acc + 1;
        y0 = band * 8;
        TST = 8 + 10;
    }

    // zero pads: pair slots 0..2 and 259..261, both buffers
    if (tx < 3) {
        f32x4 z4 = {0.f, 0.f, 0.f, 0.f};
        f32x2 z2 = {0.f, 0.f};
        A4[0][tx] = z4; A4[1][tx] = z4; A4[0][259 + tx] = z4; A4[1][259 + tx] = z4;
        B4[0][tx] = z4; B4[1][tx] = z4; B4[0][259 + tx] = z4; B4[1][259 + tx] = z4;
        Z2[0][tx] = z2; Z2[1][tx] = z2; Z2[0][259 + tx] = z2; Z2[1][259 + tx] = z2;
    }

    // 11-slot register ring of raw (a,b) pairs, statically indexed (unroll-11)
    f32x2 ra[11], rb[11];
    #pragma unroll
    for (int i = 0; i < 11; i++) { ra[i] = (f32x2){0.f, 0.f}; rb[i] = (f32x2){0.f, 0.f}; }

    float sum = 0.f;

    // prefetch first input row (r = y0 - 5)
    f32x2 aN = {0.f, 0.f}, bN = {0.f, 0.f};
    {
        int r = y0 - 5;
        if (r >= 0 && r < IMG) {
            aN = *(const f32x2*)&Ap[(long)r * IMG + x0];
            bN = *(const f32x2*)&Bp[(long)r * IMG + x0];
        }
    }

    const f32x2 C1v = {1e-4f, 1e-4f};
    const f32x2 C2v = {9e-4f, 9e-4f};

    for (int t0 = 0; t0 < TST; t0 += 11) {
        #pragma unroll
        for (int u = 0; u < 11; u++) {
            const int t = t0 + u;
            if (t < TST) {                    // block-uniform
                ra[u] = aN;
                rb[u] = bN;

                // prefetch next row (block-uniform guard); load stays in
                // flight across the row barrier (no vmcnt drain there).
                {
                    int rn = y0 - 4 + t;
                    aN = (f32x2){0.f, 0.f}; bN = (f32x2){0.f, 0.f};
                    if ((t + 1 < TST) && rn >= 0 && rn < IMG) {
                        aN = *(const f32x2*)&Ap[(long)rn * IMG + x0];
                        bN = *(const f32x2*)&Bp[(long)rn * IMG + x0];
                    }
                }

                if (t >= 10) {                // output row o = y0 + t - 10
                    // vertical 11-tap (packed): slot (u+1+j)%11 = row o-5+j
                    f32x2 m1 = {0.f, 0.f}, m2 = m1, xx = m1, yy = m1, zz = m1;
                    #pragma unroll
                    for (int j = 0; j < 11; j++) {
                        const int s = (u + 1 + j) % 11;     // compile-time
                        const f32x2 g2 = {gw.w[j], gw.w[j]};
                        f32x2 a = ra[s], b = rb[s];
                        f32x2 ga = g2 * a, gb = g2 * b;
                        m1 += ga; m2 += gb;
                        xx += ga * a; yy += gb * b; zz += ga * b;
                    }
                    const int buf = t & 1;
                    A4[buf][3 + tx] = __builtin_shufflevector(m1, m2, 0, 1, 2, 3);
                    B4[buf][3 + tx] = __builtin_shufflevector(xx, yy, 0, 1, 2, 3);
                    Z2[buf][3 + tx] = zz;
                    row_barrier();            // LDS-only: writes visible, vmem in flight

                    // horizontal 11-tap over 7 pair slots, packed coefficients.
                    // slot jj holds cols (x0-6+2jj, x0-5+2jj); for output pair
                    // (x0, x0+1): e0 coeffs (g[2jj-1], g[2jj-2]), e1 (g[2jj], g[2jj-1]).
                    f32x2 OM1 = {0.f, 0.f}, OM2 = OM1, OXX = OM1, OYY = OM1, OZZ = OM1;
                    {   // jj = 0: only e1 with (g0, 0)
                        f32x4 pa = A4[buf][tx], pb = B4[buf][tx];
                        f32x2 pz = Z2[buf][tx];
                        const f32x2 c = {gw.w[0], 0.f};
                        OM1 += c * __builtin_shufflevector(pa, pa, 1, 1);
                        OM2 += c * __builtin_shufflevector(pa, pa, 3, 3);
                        OXX += c * __builtin_shufflevector(pb, pb, 1, 1);
                        OYY += c * __builtin_shufflevector(pb, pb, 3, 3);
                        OZZ += c * __builtin_shufflevector(pz, pz, 1, 1);
                    }
                    #pragma unroll
                    for (int jj = 1; jj <= 5; jj++) {
                        f32x4 pa = A4[buf][tx + jj], pb = B4[buf][tx + jj];
                        f32x2 pz = Z2[buf][tx + jj];
                        const f32x2 cA = {gw.w[2 * jj - 1], gw.w[2 * jj - 2]};
                        const f32x2 cB = {gw.w[2 * jj],     gw.w[2 * jj - 1]};
                        OM1 += cA * __builtin_shufflevector(pa, pa, 0, 0)
                             + cB * __builtin_shufflevector(pa, pa, 1, 1);
                        OM2 += cA * __builtin_shufflevector(pa, pa, 2, 2)
                             + cB * __builtin_shufflevector(pa, pa, 3, 3);
                        OXX += cA * __builtin_shufflevector(pb, pb, 0, 0)
                             + cB * __builtin_shufflevector(pb, pb, 1, 1);
                        OYY += cA * __builtin_shufflevector(pb, pb, 2, 2)
                             + cB * __builtin_shufflevector(pb, pb, 3, 3);
                        OZZ += cA * __builtin_shufflevector(pz, pz, 0, 0)
                             + cB * __builtin_shufflevector(pz, pz, 1, 1);
                    }
                    {   // jj = 6: only e0 with (0, g10)
                        f32x4 pa = A4[buf][tx + 6], pb = B4[buf][tx + 6];
                        f32x2 pz = Z2[buf][tx + 6];
                        const f32x2 c = {0.f, gw.w[10]};
                        OM1 += c * __builtin_shufflevector(pa, pa, 0, 0);
                        OM2 += c * __builtin_shufflevector(pa, pa, 2, 2);
                        OXX += c * __builtin_shufflevector(pb, pb, 0, 0);
                        OYY += c * __builtin_shufflevector(pb, pb, 2, 2);
                        OZZ += c * __builtin_shufflevector(pz, pz, 0, 0);
                    }

                    // SSIM formula, packed where possible
                    f32x2 m1s = OM1 * OM1, m2s = OM2 * OM2, m12 = OM1 * OM2;
                    f32x2 s1 = OXX - m1s, s2 = OYY - m2s, s12 = OZZ - m12;
                    f32x2 d1 = m1s + m2s + C1v;
                    f32x2 d2 = s1 + s2 + C2v;
                    f32x2 num = (2.f * m12 + C1v) * (2.f * s12 + C2v) * (s12 + C2v);
                    float d3x = __builtin_amdgcn_sqrtf(s1.x) * __builtin_amdgcn_sqrtf(s2.x) + 9e-4f;
                    float d3y = __builtin_amdgcn_sqrtf(s1.y) * __builtin_amdgcn_sqrtf(s2.y) + 9e-4f;
                    sum += num.x * __builtin_amdgcn_rcpf(d1.x * d2.x * d3x);
                    sum += num.y * __builtin_amdgcn_rcpf(d1.y * d2.y * d3y);
                }
            }
        }
    }

    // block reduction: wave shuffle -> LDS -> one atomic per block
    for (int off = 32; off > 0; off >>= 1)
        sum += __shfl_down(sum, off, 64);
    if ((tx & 63) == 0) bsum[tx >> 6] = sum;
    __syncthreads();
    if (tx == 0) {
        float tot = bsum[0] + bsum[1] + bsum[2] + bsum[3];
        atomicAdd(accp, (double)tot);
    }
}

// b2 = mean over 16 depth slices of img2, vectorized float4 (BW-bound).
__global__ __launch_bounds__(256) void depth_mean4_kernel(
    const float4* __restrict__ img2, float4* __restrict__ b2)
{
    const int per = SLICE / 4;                       // 65536 float4 per slice
    int idx = blockIdx.x * 256 + threadIdx.x;        // 0 .. 4*per-1
    int b = idx >> 16;
    int p = idx & (per - 1);
    const float4* src = img2 + (long)b * 16 * per + p;
    float sx = 0.f, sy = 0.f, sz = 0.f, sw = 0.f;
    #pragma unroll
    for (int d = 0; d < 16; d++) {
        float4 v = src[(long)d * per];
        sx += v.x; sy += v.y; sz += v.z; sw += v.w;
    }
    float4 o; o.x = sx * 0.0625f; o.y = sy * 0.0625f; o.z = sz * 0.0625f; o.w = sw * 0.0625f;
    b2[idx] = o;
}

__global__ void finalize_kernel(const double* __restrict__ acc, float* __restrict__ out)
{
    double loss3 = 1.0 - acc[0] / (64.0 * (double)SLICE);
    double loss2 = 1.0 - acc[1] / (4.0 * (double)SLICE);
    out[0] = (float)(loss3 + loss2);
}

extern "C" void kernel_launch(void* const* d_in, const int* in_sizes, int n_in,
                              void* d_out, int out_size, void* d_ws, size_t ws_size,
                              hipStream_t stream)
{
    const float* img1_3d = (const float*)d_in[0];   // [4,1,16,512,512] -> 64 slices
    const float* img1_2d = (const float*)d_in[1];   // [4,1,512,512]
    const float* img2    = (const float*)d_in[2];   // [4,1,16,512,512]
    float* out = (float*)d_out;

    double* acc = (double*)d_ws;                    // [0]=3D sum, [1]=2D sum
    float*  b2  = (float*)((char*)d_ws + 256);      // 4 MB depth-mean buffer

    // Gaussian weights, like cv2.getGaussianKernel(11, 1.5) in double.
    G11 gw;
    {
        double g[WSZ], s = 0.0;
        for (int i = 0; i < WSZ; i++) {
            double xx = (double)i - (WSZ - 1) / 2.0;
            g[i] = std::exp(-(xx * xx) / (2.0 * 1.5 * 1.5));
            s += g[i];
        }
        for (int i = 0; i < WSZ; i++) gw.w[i] = (float)(g[i] / s);
    }

    hipMemsetAsync(acc, 0, 2 * sizeof(double), stream);

    // depth mean of img2 -> b2 (68 MB, ~12 us, proven)
    depth_mean4_kernel<<<(4 * SLICE / 4) / 256, 256, 0, stream>>>(
        (const float4*)img2, (float4*)b2);

    // merged SSIM: 1536 3D bands (64 slices x (16x22 + 8x20 rows))
    // + 256 2D bands (4 imgs x 64x8 rows) = 1792 blocks = exactly 7/CU.
    ssim_pk_kernel<<<1792, 256, 0, stream>>>(img1_3d, img2, img1_2d, b2, acc, gw);

    finalize_kernel<<<1, 1, 0, stream>>>(acc, out);
}

// Round 14
// 93.995 us; speedup vs baseline: 1.7740x; 1.1219x over previous
//
#include <hip/hip_runtime.h>
#include <cmath>

// SSIM loss, vertical-first row-sliding kernel, merged 3D+2D dispatch.
// Round-14 = round-13 math with TWO output rows per barrier interval:
// 12-slot register ring, insert 2 input rows/iter, compute 2 vertical sums,
// write row o -> LDS buffer b0 and row o+1 -> b1, ONE lgkmcnt-only barrier,
// then two INDEPENDENT horizontal+SSIM passes (2x ILP in the stall-dominated
// read/FMA section; barriers halved). 4 LDS buffer sets (even iter {0,1},
// odd {2,3}) make the pipeline race-free with a single barrier per iter:
// a wave's own lgkmcnt(0) before each barrier orders its reads before any
// later overwrite. launch_bounds(256,4): VGPR cap 128, est. use ~90 (the
// 48-VGPR f32x2 ring grows to 12 slots + 2-row accumulators) -> no spill.

#define WSZ 11
#define IMG 512
#define SLICE (IMG * IMG)

typedef float f32x2 __attribute__((ext_vector_type(2)));
typedef float f32x4 __attribute__((ext_vector_type(4)));

struct G11 { float w[WSZ]; };

// LDS-visibility-only barrier (R13): wait own LDS ops, rendezvous; vmem stays in flight.
__device__ __forceinline__ void row_barrier()
{
    asm volatile("s_waitcnt lgkmcnt(0)" ::: "memory");
    __builtin_amdgcn_s_barrier();
}

__global__ __launch_bounds__(256, 4)
void ssim_pk_kernel(const float* __restrict__ A3, const float* __restrict__ B3,
                    const float* __restrict__ A2, const float* __restrict__ B2,
                    double* __restrict__ acc, G11 gw)
{
    __shared__ f32x4 A4[4][262];   // (m1,m2) pairs, 3-slot pad each side
    __shared__ f32x4 B4[4][262];   // (xx,yy) pairs
    __shared__ f32x2 Z2[4][262];   // zz pairs
    __shared__ float bsum[4];

    const int tx = threadIdx.x;    // 0..255 = column pair index
    const int x0 = tx * 2;

    // decode work unit: [0,1536) = 3D slice-bands (24/slice: 16x22 + 8x20 rows),
    // [1536,1792) = 2D bands (4 imgs x 64 bands of 8 rows, B2 = depth mean)
    const int unit = blockIdx.x;
    const float* Ap;
    const float* Bp;
    double* accp;
    int y0, BAND;
    if (unit < 1536) {
        int slice = unit / 24;
        int band  = unit - slice * 24;
        Ap = A3 + (long)slice * SLICE;
        Bp = B3 + (long)slice * SLICE;
        accp = acc + 0;
        if (band < 16) { y0 = band * 22;              BAND = 22; }
        else           { y0 = 352 + (band - 16) * 20; BAND = 20; }
    } else {
        int uu = unit - 1536;
        int img  = uu >> 6;
        int band = uu & 63;
        Ap = A2 + (long)img * SLICE;
        Bp = B2 + (long)img * SLICE;
        accp = acc + 1;
        y0 = band * 8;
        BAND = 8;
    }
    const int ITER = BAND >> 1;    // 2 output rows per iteration

    // zero pads: pair slots 0..2 and 259..261, all 4 buffers
    if (tx < 3) {
        f32x4 z4 = {0.f, 0.f, 0.f, 0.f};
        f32x2 z2 = {0.f, 0.f};
        #pragma unroll
        for (int b = 0; b < 4; b++) {
            A4[b][tx] = z4; A4[b][259 + tx] = z4;
            B4[b][tx] = z4; B4[b][259 + tx] = z4;
            Z2[b][tx] = z2; Z2[b][259 + tx] = z2;
        }
    }

    // 12-slot register ring of raw (a,b) pairs; slot = t % 12, t = row - (y0-5)
    f32x2 ra[12], rb[12];

    float sum = 0.f;
    const f32x2 C1v = {1e-4f, 1e-4f};
    const f32x2 C2v = {9e-4f, 9e-4f};

    // warmup: insert input rows t = 0..9 (rows y0-5 .. y0+4)
    #pragma unroll
    for (int t = 0; t < 10; t++) {
        int r = y0 - 5 + t;
        f32x2 a = {0.f, 0.f}, b = {0.f, 0.f};
        if (r >= 0) {                       // r < IMG always in warmup
            a = *(const f32x2*)&Ap[(long)r * IMG + x0];
            b = *(const f32x2*)&Bp[(long)r * IMG + x0];
        }
        ra[t] = a; rb[t] = b;
    }
    ra[10] = (f32x2){0.f, 0.f}; rb[10] = (f32x2){0.f, 0.f};
    ra[11] = (f32x2){0.f, 0.f}; rb[11] = (f32x2){0.f, 0.f};

    // prefetch iteration 0's two input rows (t = 10, 11 -> rows y0+5, y0+6)
    f32x2 aN0 = {0.f, 0.f}, bN0 = aN0, aN1 = aN0, bN1 = aN0;
    {
        int r0 = y0 + 5, r1 = y0 + 6;
        if (r0 < IMG) { aN0 = *(const f32x2*)&Ap[(long)r0 * IMG + x0];
                        bN0 = *(const f32x2*)&Bp[(long)r0 * IMG + x0]; }
        if (r1 < IMG) { aN1 = *(const f32x2*)&Ap[(long)r1 * IMG + x0];
                        bN1 = *(const f32x2*)&Bp[(long)r1 * IMG + x0]; }
    }

    // vertical 11-tap for one output row; slots (base+j)%12, weights g[j]
    auto vpass = [&](int base, int buf) {
        f32x2 m1 = {0.f, 0.f}, m2 = m1, xx = m1, yy = m1, zz = m1;
        #pragma unroll
        for (int j = 0; j < 11; j++) {
            const int s = (base + j) % 12;           // compile-time
            const f32x2 g2 = {gw.w[j], gw.w[j]};
            f32x2 a = ra[s], b = rb[s];
            f32x2 ga = g2 * a, gb = g2 * b;
            m1 += ga; m2 += gb;
            xx += ga * a; yy += gb * b; zz += ga * b;
        }
        A4[buf][3 + tx] = __builtin_shufflevector(m1, m2, 0, 1, 2, 3);
        B4[buf][3 + tx] = __builtin_shufflevector(xx, yy, 0, 1, 2, 3);
        Z2[buf][3 + tx] = zz;
    };

    // horizontal 11-tap + SSIM for one buffered row
    auto hpass = [&](int buf) {
        f32x2 OM1 = {0.f, 0.f}, OM2 = OM1, OXX = OM1, OYY = OM1, OZZ = OM1;
        {   // jj = 0: only e1 with (g0, 0)
            f32x4 pa = A4[buf][tx], pb = B4[buf][tx];
            f32x2 pz = Z2[buf][tx];
            const f32x2 c = {gw.w[0], 0.f};
            OM1 += c * __builtin_shufflevector(pa, pa, 1, 1);
            OM2 += c * __builtin_shufflevector(pa, pa, 3, 3);
            OXX += c * __builtin_shufflevector(pb, pb, 1, 1);
            OYY += c * __builtin_shufflevector(pb, pb, 3, 3);
            OZZ += c * __builtin_shufflevector(pz, pz, 1, 1);
        }
        #pragma unroll
        for (int jj = 1; jj <= 5; jj++) {
            f32x4 pa = A4[buf][tx + jj], pb = B4[buf][tx + jj];
            f32x2 pz = Z2[buf][tx + jj];
            const f32x2 cA = {gw.w[2 * jj - 1], gw.w[2 * jj - 2]};
            const f32x2 cB = {gw.w[2 * jj],     gw.w[2 * jj - 1]};
            OM1 += cA * __builtin_shufflevector(pa, pa, 0, 0)
                 + cB * __builtin_shufflevector(pa, pa, 1, 1);
            OM2 += cA * __builtin_shufflevector(pa, pa, 2, 2)
                 + cB * __builtin_shufflevector(pa, pa, 3, 3);
            OXX += cA * __builtin_shufflevector(pb, pb, 0, 0)
                 + cB * __builtin_shufflevector(pb, pb, 1, 1);
            OYY += cA * __builtin_shufflevector(pb, pb, 2, 2)
                 + cB * __builtin_shufflevector(pb, pb, 3, 3);
            OZZ += cA * __builtin_shufflevector(pz, pz, 0, 0)
                 + cB * __builtin_shufflevector(pz, pz, 1, 1);
        }
        {   // jj = 6: only e0 with (0, g10)
            f32x4 pa = A4[buf][tx + 6], pb = B4[buf][tx + 6];
            f32x2 pz = Z2[buf][tx + 6];
            const f32x2 c = {0.f, gw.w[10]};
            OM1 += c * __builtin_shufflevector(pa, pa, 0, 0);
            OM2 += c * __builtin_shufflevector(pa, pa, 2, 2);
            OXX += c * __builtin_shufflevector(pb, pb, 0, 0);
            OYY += c * __builtin_shufflevector(pb, pb, 2, 2);
            OZZ += c * __builtin_shufflevector(pz, pz, 0, 0);
        }
        f32x2 m1s = OM1 * OM1, m2s = OM2 * OM2, m12 = OM1 * OM2;
        f32x2 s1 = OXX - m1s, s2 = OYY - m2s, s12 = OZZ - m12;
        f32x2 d1 = m1s + m2s + C1v;
        f32x2 d2 = s1 + s2 + C2v;
        f32x2 num = (2.f * m12 + C1v) * (2.f * s12 + C2v) * (s12 + C2v);
        float d3x = __builtin_amdgcn_sqrtf(s1.x) * __builtin_amdgcn_sqrtf(s2.x) + 9e-4f;
        float d3y = __builtin_amdgcn_sqrtf(s1.y) * __builtin_amdgcn_sqrtf(s2.y) + 9e-4f;
        sum += num.x * __builtin_amdgcn_rcpf(d1.x * d2.x * d3x);
        sum += num.y * __builtin_amdgcn_rcpf(d1.y * d2.y * d3y);
    };

    // main loop: iteration k emits output rows y0+2k, y0+2k+1
    for (int kk = 0; kk < ITER; kk += 6) {
        #pragma unroll
        for (int u = 0; u < 6; u++) {
            const int k = kk + u;
            if (k < ITER) {                       // block-uniform
                // insert this iteration's two rows (t = 10+2k, 11+2k)
                const int s0 = (10 + 2 * u) % 12; // kk%6==0 -> static
                const int s1 = (11 + 2 * u) % 12;
                ra[s0] = aN0; rb[s0] = bN0;
                ra[s1] = aN1; rb[s1] = bN1;

                // prefetch next iteration's two rows (stay in flight across barrier)
                {
                    int r0 = y0 + 7 + 2 * k, r1 = r0 + 1;
                    aN0 = (f32x2){0.f, 0.f}; bN0 = aN0; aN1 = aN0; bN1 = aN0;
                    if (k + 1 < ITER) {
                        if (r0 < IMG) { aN0 = *(const f32x2*)&Ap[(long)r0 * IMG + x0];
                                        bN0 = *(const f32x2*)&Bp[(long)r0 * IMG + x0]; }
                        if (r1 < IMG) { aN1 = *(const f32x2*)&Ap[(long)r1 * IMG + x0];
                                        bN1 = *(const f32x2*)&Bp[(long)r1 * IMG + x0]; }
                    }
                }

                // two vertical sums -> two buffers; one barrier; two h-passes
                const int b0 = (u & 1) * 2;       // even k -> {0,1}, odd -> {2,3}
                vpass(2 * u,     b0);             // row o   uses slots (2k+j)%12
                vpass(2 * u + 1, b0 + 1);         // row o+1 uses slots (2k+1+j)%12
                row_barrier();
                hpass(b0);
                hpass(b0 + 1);
            }
        }
    }

    // block reduction: wave shuffle -> LDS -> one atomic per block
    for (int off = 32; off > 0; off >>= 1)
        sum += __shfl_down(sum, off, 64);
    if ((tx & 63) == 0) bsum[tx >> 6] = sum;
    __syncthreads();
    if (tx == 0) {
        float tot = bsum[0] + bsum[1] + bsum[2] + bsum[3];
        atomicAdd(accp, (double)tot);
    }
}

// b2 = mean over 16 depth slices of img2, vectorized float4 (BW-bound).
__global__ __launch_bounds__(256) void depth_mean4_kernel(
    const float4* __restrict__ img2, float4* __restrict__ b2)
{
    const int per = SLICE / 4;                       // 65536 float4 per slice
    int idx = blockIdx.x * 256 + threadIdx.x;        // 0 .. 4*per-1
    int b = idx >> 16;
    int p = idx & (per - 1);
    const float4* src = img2 + (long)b * 16 * per + p;
    float sx = 0.f, sy = 0.f, sz = 0.f, sw = 0.f;
    #pragma unroll
    for (int d = 0; d < 16; d++) {
        float4 v = src[(long)d * per];
        sx += v.x; sy += v.y; sz += v.z; sw += v.w;
    }
    float4 o; o.x = sx * 0.0625f; o.y = sy * 0.0625f; o.z = sz * 0.0625f; o.w = sw * 0.0625f;
    b2[idx] = o;
}

__global__ void finalize_kernel(const double* __restrict__ acc, float* __restrict__ out)
{
    double loss3 = 1.0 - acc[0] / (64.0 * (double)SLICE);
    double loss2 = 1.0 - acc[1] / (4.0 * (double)SLICE);
    out[0] = (float)(loss3 + loss2);
}

extern "C" void kernel_launch(void* const* d_in, const int* in_sizes, int n_in,
                              void* d_out, int out_size, void* d_ws, size_t ws_size,
                              hipStream_t stream)
{
    const float* img1_3d = (const float*)d_in[0];   // [4,1,16,512,512] -> 64 slices
    const float* img1_2d = (const float*)d_in[1];   // [4,1,512,512]
    const float* img2    = (const float*)d_in[2];   // [4,1,16,512,512]
    float* out = (float*)d_out;

    double* acc = (double*)d_ws;                    // [0]=3D sum, [1]=2D sum
    float*  b2  = (float*)((char*)d_ws + 256);      // 4 MB depth-mean buffer

    // Gaussian weights, like cv2.getGaussianKernel(11, 1.5) in double.
    G11 gw;
    {
        double g[WSZ], s = 0.0;
        for (int i = 0; i < WSZ; i++) {
            double xx = (double)i - (WSZ - 1) / 2.0;
            g[i] = std::exp(-(xx * xx) / (2.0 * 1.5 * 1.5));
            s += g[i];
        }
        for (int i = 0; i < WSZ; i++) gw.w[i] = (float)(g[i] / s);
    }

    hipMemsetAsync(acc, 0, 2 * sizeof(double), stream);

    // depth mean of img2 -> b2 (68 MB, ~12 us, proven)
    depth_mean4_kernel<<<(4 * SLICE / 4) / 256, 256, 0, stream>>>(
        (const float4*)img2, (float4*)b2);

    // merged SSIM: 1536 3D bands (64 slices x (16x22 + 8x20 rows))
    // + 256 2D bands (4 imgs x 64x8 rows) = 1792 blocks.
    ssim_pk_kernel<<<1792, 256, 0, stream>>>(img1_3d, img2, img1_2d, b2, acc, gw);

    finalize_kernel<<<1, 1, 0, stream>>>(acc, out);
}